// Round 20
// baseline (114.249 us; speedup 1.0000x reference)
//
#include <hip/hip_runtime.h>
#include <hip/hip_bf16.h>
#include <math.h>

typedef unsigned short ushort_t;
typedef __attribute__((ext_vector_type(8))) short bf16x8;
typedef __attribute__((ext_vector_type(4))) float f32x4;

#define MFMA16(a,b,c) __builtin_amdgcn_mfma_f32_16x16x32_bf16(a,b,c,0,0,0)
#define QSCALE 0.1803368801111204f   /* 0.125 * log2(e) : softmax in base-2 */

typedef unsigned int u32;
typedef __attribute__((address_space(1))) const u32* gp1_t;
typedef __attribute__((address_space(3))) u32* lp3_t;

__device__ __forceinline__ void async_copy16(void* l, const void* g) {
    __builtin_amdgcn_global_load_lds((gp1_t)g, (lp3_t)l, 16, 0, 0);
}

__device__ __forceinline__ ushort_t f2bf(float f) {
    unsigned u = __float_as_uint(f);
    unsigned r = u + 0x7fffu + ((u >> 16) & 1u);
    return (ushort_t)(r >> 16);
}

// ---------------------------------------------------------------- convert
__global__ __launch_bounds__(256) void cvt_kernel(
    const float* __restrict__ x,  const float* __restrict__ wq,
    const float* __restrict__ wk, const float* __restrict__ wv,
    const float* __restrict__ wo, ushort_t* __restrict__ dst)
{
    size_t base = ((size_t)blockIdx.x * 256 + threadIdx.x) * 8;
    const float* src; size_t off;
    if      (base < 4194304ul) { src = x;  off = base; }
    else if (base < 5242880ul) { src = wq; off = base - 4194304ul; }
    else if (base < 6291456ul) { src = wk; off = base - 5242880ul; }
    else if (base < 7340032ul) { src = wv; off = base - 6291456ul; }
    else                       { src = wo; off = base - 7340032ul; }
    float4 a = *(const float4*)(src + off);
    float4 b = *(const float4*)(src + off + 4);
    struct alignas(16) U8 { ushort_t v[8]; } o;
    o.v[0]=f2bf(a.x); o.v[1]=f2bf(a.y); o.v[2]=f2bf(a.z); o.v[3]=f2bf(a.w);
    o.v[4]=f2bf(b.x); o.v[5]=f2bf(b.y); o.v[6]=f2bf(b.z); o.v[7]=f2bf(b.w);
    *(U8*)(dst + base) = o;
}

// ---------------------------------------------------------------- GEMM
// 256 threads = 4 waves (2x2), wave tile 64x64 (acc[4][4]): 8 ds_read_b128
// per 16 MFMA (0.5 KB/MFMA, 1.5x better than 32x64). BK=32, LDS 32 KB ->
// 3 blocks/CU resident (1 wave/SIMD per block, ~150 VGPR -> 3 waves/SIMD).
// Counted vmcnt(4): prefetch stays in flight across barriers.
__global__ __launch_bounds__(256) void gemm_bt(
    const ushort_t* __restrict__ A, const ushort_t* __restrict__ B,
    ushort_t* __restrict__ Oq, ushort_t* __restrict__ Ok,
    ushort_t* __restrict__ Ovt, float* __restrict__ Of, int is_out)
{
    __shared__ ushort_t As[2][128 * 32];   // 8 KB per buf
    __shared__ ushort_t Bs[2][128 * 32];
    const int t = threadIdx.x, l = t & 63, w = t >> 6;
    const int l4 = l >> 4, lm = l & 15;
    const int wr = w >> 1, wc = w & 1;       // 2 x 2 waves

    const int nwg = gridDim.x * gridDim.y;
    const int orig = (int)blockIdx.y * gridDim.x + (int)blockIdx.x;
    const int qq = nwg >> 3;
    const int swz = (orig & 7) * qq + (orig >> 3);
    const int n0 = (swz % gridDim.x) * 128;
    const int m0 = (swz / gridDim.x) * 128;

    const int srow = t >> 2, scol = t & 3;   // 64 rows covered; 2 halves below
    f32x4 acc[4][4] = {};

    // prologue: stage K-tile 0 -> buf 0 (2 A + 2 B loads/thread)
    #pragma unroll
    for (int i = 0; i < 2; ++i) {
        const int row = i * 64 + srow;
        const int c = scol ^ ((row >> 1) & 3);
        async_copy16((char*)&As[0][0] + i * 4096 + t * 16,
                     A + (size_t)(m0 + row) * 1024 + c * 8);
        async_copy16((char*)&Bs[0][0] + i * 4096 + t * 16,
                     B + (size_t)(n0 + row) * 1024 + c * 8);
    }

    for (int kt = 0; kt < 32; ++kt) {
        const int cur = kt & 1;
        if (kt + 1 < 32) {
            const int k0 = (kt + 1) * 32;
            #pragma unroll
            for (int i = 0; i < 2; ++i) {
                const int row = i * 64 + srow;
                const int c = scol ^ ((row >> 1) & 3);
                async_copy16((char*)&As[cur ^ 1][0] + i * 4096 + t * 16,
                             A + (size_t)(m0 + row) * 1024 + k0 + c * 8);
                async_copy16((char*)&Bs[cur ^ 1][0] + i * 4096 + t * 16,
                             B + (size_t)(n0 + row) * 1024 + k0 + c * 8);
            }
            asm volatile("s_waitcnt vmcnt(4)" ::: "memory");
        } else {
            asm volatile("s_waitcnt vmcnt(0)" ::: "memory");
        }
        __builtin_amdgcn_s_barrier();

        bf16x8 af[4], bfr[4];
        #pragma unroll
        for (int mi = 0; mi < 4; ++mi) {
            const int row = wr * 64 + mi * 16 + lm;
            af[mi] = *(const bf16x8*)(&As[cur][0] + row * 32 +
                      ((l4 ^ ((row >> 1) & 3)) << 3));
        }
        #pragma unroll
        for (int ni = 0; ni < 4; ++ni) {
            const int row = wc * 64 + ni * 16 + lm;
            bfr[ni] = *(const bf16x8*)(&Bs[cur][0] + row * 32 +
                      ((l4 ^ ((row >> 1) & 3)) << 3));
        }
        #pragma unroll
        for (int mi = 0; mi < 4; ++mi)
            #pragma unroll
            for (int ni = 0; ni < 4; ++ni)
                acc[mi][ni] = MFMA16(af[mi], bfr[ni], acc[mi][ni]);

        asm volatile("s_waitcnt lgkmcnt(0)" ::: "memory");
        __builtin_amdgcn_s_barrier();
    }

    const int mb = m0 + wr * 64, nb = n0 + wc * 64;
    if (is_out) {
        #pragma unroll
        for (int mi = 0; mi < 4; ++mi)
            #pragma unroll
            for (int ni = 0; ni < 4; ++ni) {
                const int n = nb + ni * 16 + lm;
                const int mr = mb + mi * 16 + l4 * 4;
                #pragma unroll
                for (int r = 0; r < 4; ++r)
                    Of[(size_t)(mr + r) * 1024 + n] = acc[mi][ni][r];
            }
    } else if (nb >= 2048) {            // V^T region
        #pragma unroll
        for (int mi = 0; mi < 4; ++mi)
            #pragma unroll
            for (int ni = 0; ni < 4; ++ni) {
                const int nv = nb - 2048 + ni * 16 + lm;
                const int m = mb + mi * 16 + l4 * 4;
                const int b = m >> 11, s = m & 2047, h = nv >> 6, d = nv & 63;
                ushort4 pk;
                pk.x = f2bf(acc[mi][ni][0]); pk.y = f2bf(acc[mi][ni][1]);
                pk.z = f2bf(acc[mi][ni][2]); pk.w = f2bf(acc[mi][ni][3]);
                *(ushort4*)(Ovt + (((size_t)(b * 16 + h) * 64 + d) * 2048 + s)) = pk;
            }
    } else {                            // Q (scaled) or K region
        ushort_t* O = (nb < 1024) ? Oq : Ok;
        const float qs = (nb < 1024) ? (float)QSCALE : 1.0f;
        const int nbase = nb & 1023;
        #pragma unroll
        for (int mi = 0; mi < 4; ++mi)
            #pragma unroll
            for (int ni = 0; ni < 4; ++ni) {
                const int n = nbase + ni * 16 + lm;
                const int h = n >> 6, d = n & 63;
                #pragma unroll
                for (int r = 0; r < 4; ++r) {
                    const int m = mb + mi * 16 + l4 * 4 + r;
                    const int b = m >> 11, s = m & 2047;
                    O[((size_t)(b * 16 + h) * 2048 + s) * 64 + d] =
                        f2bf(acc[mi][ni][r] * qs);
                }
            }
    }
}

// ---------------------------------------------------------------- attention
// (R18 structure, kept) Zero-shift softmax + 64KB LDS, 2 kv-groups x 4 q-waves.
__global__ __launch_bounds__(512) void attn_kernel(
    const ushort_t* __restrict__ Qg, const ushort_t* __restrict__ Kg,
    const ushort_t* __restrict__ Vtg, ushort_t* __restrict__ Og)
{
    __shared__ char smem[65536];
    // K: [g][buf] at g*16384 + buf*8192 ; V: 32768 + g*8192 ; P: 49152 + w*2048

    const int t = threadIdx.x, l = t & 63, w = t >> 6;
    const int l4 = l >> 4, lm = l & 15;
    const int kvg = w >> 2, qg = w & 3;        // 2 kv-groups x 4 q-waves
    const int bh = blockIdx.x;
    const int qt = 15 - (int)blockIdx.y;       // heavy q-tiles first
    const int q0w = qt * 128 + qg * 32;

    const ushort_t* Kbh = Kg + (size_t)bh * 2048 * 64;
    const ushort_t* Vbh = Vtg + (size_t)bh * 64 * 2048;

    bf16x8 qf[2][2];
    #pragma unroll
    for (int qi = 0; qi < 2; ++qi) {
        const ushort_t* qp = Qg + ((size_t)bh * 2048 + q0w + qi * 16 + lm) * 64 + l4 * 8;
        qf[qi][0] = *(const bf16x8*)qp;
        qf[qi][1] = *(const bf16x8*)(qp + 32);
    }
    bf16x8 ones;
    #pragma unroll
    for (int i = 0; i < 8; ++i) ones[i] = (short)0x3F80;

    f32x4 o[2][4] = {};
    f32x4 ol[2] = {};

    const int tg = t & 255;
    const int sr0 = tg >> 3, sc0 = tg & 7;
    const ushort_t* kp[2]; const ushort_t* vp[2];
    char* kd[2]; char* vd[2];
    #pragma unroll
    for (int i = 0; i < 2; ++i) {
        const int row = i * 32 + sr0;
        const int c = sc0 ^ (row & 7);
        kp[i] = Kbh + row * 64 + c * 8;
        vp[i] = Vbh + (size_t)row * 2048 + c * 8;
        kd[i] = smem + kvg * 16384 + i * 4096 + tg * 16;
        vd[i] = smem + 32768 + kvg * 8192 + i * 4096 + tg * 16;
    }
    const int pswz = (lm & 7) << 4;
    char* Pw = smem + 49152 + w * 2048;
    const ushort_t* Vgrp = (const ushort_t*)(smem + 32768 + kvg * 8192);

    const int nst = qt + 1;
    {   // prologue: stage K(0) -> buf 0
        const int kv0p = kvg * 64;
        #pragma unroll
        for (int i = 0; i < 2; ++i)
            async_copy16(kd[i], kp[i] + (size_t)kv0p * 64);
    }

    for (int s = 0; s < nst; ++s) {
        const int cur = s & 1;
        const int kv0 = (2 * s + kvg) * 64;
        #pragma unroll
        for (int i = 0; i < 2; ++i)
            async_copy16(vd[i], vp[i] + kv0);
        if (s + 1 < nst) {
            const int kv0n = (2 * (s + 1) + kvg) * 64;
            #pragma unroll
            for (int i = 0; i < 2; ++i)
                async_copy16(kd[i] + (cur ^ 1) * 8192, kp[i] + (size_t)kv0n * 64);
            asm volatile("s_waitcnt vmcnt(4)" ::: "memory");
        } else {
            asm volatile("s_waitcnt vmcnt(2)" ::: "memory");
        }
        __builtin_amdgcn_s_barrier();          // B1: K(t) visible

        const bool active = (s + 1 < nst) || (q0w + 31 >= kv0);
        const bool last = (s + 1 == nst);
        const ushort_t* Kgrp = (const ushort_t*)(smem + kvg * 16384 + cur * 8192);

        f32x4 sf[2][4];
        if (active) {
            #pragma unroll
            for (int qi = 0; qi < 2; ++qi)
                #pragma unroll
                for (int cf = 0; cf < 4; ++cf) sf[qi][cf] = (f32x4){0,0,0,0};
            #pragma unroll
            for (int ks = 0; ks < 2; ++ks)
                #pragma unroll
                for (int cf = 0; cf < 4; ++cf) {
                    const int rowK = cf * 16 + lm;
                    const int ch = l4 + 4 * ks;
                    bf16x8 kf = *(const bf16x8*)(Kgrp + rowK * 64 + ((ch ^ (rowK & 7)) << 3));
                    sf[0][cf] = MFMA16(kf, qf[0][ks], sf[0][cf]);
                    sf[1][cf] = MFMA16(kf, qf[1][ks], sf[1][cf]);
                }
            {
                const int qrow = q0w + 0 * 16 + lm;
                #pragma unroll
                for (int cf = 0; cf < 4; ++cf) {
                    f32x4 sv = sf[0][cf];
                    if (last) {
                        #pragma unroll
                        for (int r = 0; r < 4; ++r)
                            if (kv0 + cf * 16 + l4 * 4 + r > qrow) sv[r] = -30000.f;
                    }
                    float p0 = __builtin_amdgcn_exp2f(sv[0]);
                    float p1 = __builtin_amdgcn_exp2f(sv[1]);
                    float p2 = __builtin_amdgcn_exp2f(sv[2]);
                    float p3 = __builtin_amdgcn_exp2f(sv[3]);
                    __hip_bfloat162 b01 = __float22bfloat162_rn(make_float2(p0, p1));
                    __hip_bfloat162 b23 = __float22bfloat162_rn(make_float2(p2, p3));
                    uint2 pkv;
                    __builtin_memcpy(&pkv.x, &b01, 4);
                    __builtin_memcpy(&pkv.y, &b23, 4);
                    *(uint2*)(Pw + ((lm * 128 + cf * 32 + l4 * 8) ^ pswz)) = pkv;
                }
            }
        }
        asm volatile("s_waitcnt vmcnt(2)" ::: "memory");
        if (last) asm volatile("s_waitcnt vmcnt(0)" ::: "memory");
        __builtin_amdgcn_s_barrier();          // B2: V(t) visible

        if (active) {
            #pragma unroll
            for (int ks = 0; ks < 2; ++ks) {
                bf16x8 pf = *(const bf16x8*)(Pw + ((lm * 128 + ks * 64 + l4 * 16) ^ pswz));
                #pragma unroll
                for (int df = 0; df < 4; ++df) {
                    const int rowV = df * 16 + lm;
                    const int ch = l4 + 4 * ks;
                    bf16x8 vf = *(const bf16x8*)(Vgrp + rowV * 64 + ((ch ^ (rowV & 7)) << 3));
                    o[0][df] = MFMA16(vf, pf, o[0][df]);
                }
                ol[0] = MFMA16(ones, pf, ol[0]);
            }
            {
                const int qrow = q0w + 1 * 16 + lm;
                #pragma unroll
                for (int cf = 0; cf < 4; ++cf) {
                    f32x4 sv = sf[1][cf];
                    if (last) {
                        #pragma unroll
                        for (int r = 0; r < 4; ++r)
                            if (kv0 + cf * 16 + l4 * 4 + r > qrow) sv[r] = -30000.f;
                    }
                    float p0 = __builtin_amdgcn_exp2f(sv[0]);
                    float p1 = __builtin_amdgcn_exp2f(sv[1]);
                    float p2 = __builtin_amdgcn_exp2f(sv[2]);
                    float p3 = __builtin_amdgcn_exp2f(sv[3]);
                    __hip_bfloat162 b01 = __float22bfloat162_rn(make_float2(p0, p1));
                    __hip_bfloat162 b23 = __float22bfloat162_rn(make_float2(p2, p3));
                    uint2 pkv;
                    __builtin_memcpy(&pkv.x, &b01, 4);
                    __builtin_memcpy(&pkv.y, &b23, 4);
                    *(uint2*)(Pw + ((lm * 128 + cf * 32 + l4 * 8) ^ pswz)) = pkv;
                }
            }
            #pragma unroll
            for (int ks = 0; ks < 2; ++ks) {
                bf16x8 pf = *(const bf16x8*)(Pw + ((lm * 128 + ks * 64 + l4 * 16) ^ pswz));
                #pragma unroll
                for (int df = 0; df < 4; ++df) {
                    const int rowV = df * 16 + lm;
                    const int ch = l4 + 4 * ks;
                    bf16x8 vf = *(const bf16x8*)(Vgrp + rowV * 64 + ((ch ^ (rowV & 7)) << 3));
                    o[1][df] = MFMA16(vf, pf, o[1][df]);
                }
                ol[1] = MFMA16(ones, pf, ol[1]);
            }
        }
        asm volatile("s_waitcnt lgkmcnt(0)" ::: "memory");
        __builtin_amdgcn_s_barrier();          // B3: WAR fence
    }

    // ---- merge: plain sum (both groups share the zero shift) ----
    float* sc = (float*)smem;
    const int mb_ = (qg * 64 + l) * 35;
    if (kvg == 1) {
        #pragma unroll
        for (int qi = 0; qi < 2; ++qi) {
            #pragma unroll
            for (int df = 0; df < 4; ++df)
                #pragma unroll
                for (int r = 0; r < 4; ++r)
                    sc[mb_ + qi * 17 + df * 4 + r] = o[qi][df][r];
            sc[mb_ + qi * 17 + 16] = ol[qi][0];
        }
    }
    __syncthreads();
    if (kvg == 0) {
        const int b = bh >> 4, h = bh & 15;
        #pragma unroll
        for (int qi = 0; qi < 2; ++qi) {
            const float lB = sc[mb_ + qi * 17 + 16];
            const float inv = 1.f / (ol[qi][0] + lB);
            const int srow_o = q0w + qi * 16 + lm;
            #pragma unroll
            for (int df = 0; df < 4; ++df) {
                ushort4 pk4;
                float v0 = (o[qi][df][0] + sc[mb_ + qi * 17 + df * 4 + 0]) * inv;
                float v1 = (o[qi][df][1] + sc[mb_ + qi * 17 + df * 4 + 1]) * inv;
                float v2 = (o[qi][df][2] + sc[mb_ + qi * 17 + df * 4 + 2]) * inv;
                float v3 = (o[qi][df][3] + sc[mb_ + qi * 17 + df * 4 + 3]) * inv;
                pk4.x = f2bf(v0); pk4.y = f2bf(v1); pk4.z = f2bf(v2); pk4.w = f2bf(v3);
                *(ushort4*)&Og[((size_t)(b * 2048 + srow_o)) * 1024 + h * 64 + df * 16 + l4 * 4] = pk4;
            }
        }
    }
}

// ---------------------------------------------------------------- launch
extern "C" void kernel_launch(void* const* d_in, const int* in_sizes, int n_in,
                              void* d_out, int out_size, void* d_ws, size_t ws_size,
                              hipStream_t stream)
{
    const float* x  = (const float*)d_in[0];
    const float* Wq = (const float*)d_in[1];
    const float* Wk = (const float*)d_in[2];
    const float* Wv = (const float*)d_in[3];
    const float* Wo = (const float*)d_in[4];

    ushort_t* ws  = (ushort_t*)d_ws;
    ushort_t* xb  = ws;
    ushort_t* wqb = ws + 4194304;          // Wq|Wk|Wv contiguous = [3072][1024]
    ushort_t* wob = ws + 7340032;
    ushort_t* Qw  = ws + 8388608;          // [bh][s][64] (pre-scaled)
    ushort_t* Kw  = ws + 12582912;         // [bh][s][64]
    ushort_t* Vtw = ws + 16777216;         // [bh][d][s]
    ushort_t* Aow = ws + 20971520;         // [b][s][1024]

    cvt_kernel<<<4096, 256, 0, stream>>>(x, Wq, Wk, Wv, Wo, ws);
    gemm_bt<<<dim3(24, 32), 256, 0, stream>>>(xb, wqb, Qw, Kw, Vtw, nullptr, 0);
    attn_kernel<<<dim3(32, 16), 512, 0, stream>>>(Qw, Kw, Vtw, Aow);
    gemm_bt<<<dim3(8, 32), 256, 0, stream>>>(Aow, wob, nullptr, nullptr, nullptr,
                                             (float*)d_out, 1);
}

// Round 21
// 99.875 us; speedup vs baseline: 1.1439x; 1.1439x over previous
//
#include <hip/hip_runtime.h>
#include <hip/hip_bf16.h>
#include <math.h>

typedef unsigned short ushort_t;
typedef __attribute__((ext_vector_type(8))) short bf16x8;
typedef __attribute__((ext_vector_type(4))) float f32x4;

#define MFMA16(a,b,c) __builtin_amdgcn_mfma_f32_16x16x32_bf16(a,b,c,0,0,0)
#define QSCALE 0.1803368801111204f   /* 0.125 * log2(e) : softmax in base-2 */

typedef unsigned int u32;
typedef __attribute__((address_space(1))) const u32* gp1_t;
typedef __attribute__((address_space(3))) u32* lp3_t;

__device__ __forceinline__ void async_copy16(void* l, const void* g) {
    __builtin_amdgcn_global_load_lds((gp1_t)g, (lp3_t)l, 16, 0, 0);
}

__device__ __forceinline__ ushort_t f2bf(float f) {
    unsigned u = __float_as_uint(f);
    unsigned r = u + 0x7fffu + ((u >> 16) & 1u);
    return (ushort_t)(r >> 16);
}

// ---------------------------------------------------------------- convert
__global__ __launch_bounds__(256) void cvt_kernel(
    const float* __restrict__ x,  const float* __restrict__ wq,
    const float* __restrict__ wk, const float* __restrict__ wv,
    const float* __restrict__ wo, ushort_t* __restrict__ dst)
{
    size_t base = ((size_t)blockIdx.x * 256 + threadIdx.x) * 8;
    const float* src; size_t off;
    if      (base < 4194304ul) { src = x;  off = base; }
    else if (base < 5242880ul) { src = wq; off = base - 4194304ul; }
    else if (base < 6291456ul) { src = wk; off = base - 5242880ul; }
    else if (base < 7340032ul) { src = wv; off = base - 6291456ul; }
    else                       { src = wo; off = base - 7340032ul; }
    float4 a = *(const float4*)(src + off);
    float4 b = *(const float4*)(src + off + 4);
    struct alignas(16) U8 { ushort_t v[8]; } o;
    o.v[0]=f2bf(a.x); o.v[1]=f2bf(a.y); o.v[2]=f2bf(a.z); o.v[3]=f2bf(a.w);
    o.v[4]=f2bf(b.x); o.v[5]=f2bf(b.y); o.v[6]=f2bf(b.z); o.v[7]=f2bf(b.w);
    *(U8*)(dst + base) = o;
}

// ---------------------------------------------------------------- GEMM
// (R19 proven) BK=32, LDS 32KB total, 512 threads = 8 waves (4x2), wave
// tile 32x64. [128][32] tiles, XOR swizzle c^=(row>>1)&3 -> 2-way-free
// ds_read_b128. 1 A + 1 B load/thread/step, counted vmcnt(2).
__global__ __launch_bounds__(512) void gemm_bt(
    const ushort_t* __restrict__ A, const ushort_t* __restrict__ B,
    ushort_t* __restrict__ Oq, ushort_t* __restrict__ Ok,
    ushort_t* __restrict__ Ovt, float* __restrict__ Of, int is_out)
{
    __shared__ ushort_t As[2][128 * 32];   // 8 KB per buf
    __shared__ ushort_t Bs[2][128 * 32];
    const int t = threadIdx.x, l = t & 63, w = t >> 6;
    const int l4 = l >> 4, lm = l & 15;
    const int wr = w >> 1, wc = w & 1;       // 4 x 2 waves

    const int nwg = gridDim.x * gridDim.y;
    const int orig = (int)blockIdx.y * gridDim.x + (int)blockIdx.x;
    const int qq = nwg >> 3;
    const int swz = (orig & 7) * qq + (orig >> 3);
    const int n0 = (swz % gridDim.x) * 128;
    const int m0 = (swz / gridDim.x) * 128;

    const int srow = t >> 2, scol = t & 3;   // 128 rows x 4 chunks(16B)
    const int sc = scol ^ ((srow >> 1) & 3); // inverse-swizzled source chunk

    f32x4 acc[2][4] = {};

    // prologue: stage K-tile 0 -> buf 0 (1 load/thread per matrix)
    async_copy16((char*)&As[0][0] + t * 16,
                 A + (size_t)(m0 + srow) * 1024 + sc * 8);
    async_copy16((char*)&Bs[0][0] + t * 16,
                 B + (size_t)(n0 + srow) * 1024 + sc * 8);

    for (int kt = 0; kt < 32; ++kt) {
        const int cur = kt & 1;
        if (kt + 1 < 32) {
            const int k0 = (kt + 1) * 32;
            async_copy16((char*)&As[cur ^ 1][0] + t * 16,
                         A + (size_t)(m0 + srow) * 1024 + k0 + sc * 8);
            async_copy16((char*)&Bs[cur ^ 1][0] + t * 16,
                         B + (size_t)(n0 + srow) * 1024 + k0 + sc * 8);
            asm volatile("s_waitcnt vmcnt(2)" ::: "memory");
        } else {
            asm volatile("s_waitcnt vmcnt(0)" ::: "memory");
        }
        __builtin_amdgcn_s_barrier();

        bf16x8 af[2], bfr[4];
        #pragma unroll
        for (int mi = 0; mi < 2; ++mi) {
            const int row = wr * 32 + mi * 16 + lm;
            af[mi] = *(const bf16x8*)(&As[cur][0] + row * 32 +
                      ((l4 ^ ((row >> 1) & 3)) << 3));
        }
        #pragma unroll
        for (int ni = 0; ni < 4; ++ni) {
            const int row = wc * 64 + ni * 16 + lm;
            bfr[ni] = *(const bf16x8*)(&Bs[cur][0] + row * 32 +
                      ((l4 ^ ((row >> 1) & 3)) << 3));
        }
        #pragma unroll
        for (int mi = 0; mi < 2; ++mi)
            #pragma unroll
            for (int ni = 0; ni < 4; ++ni)
                acc[mi][ni] = MFMA16(af[mi], bfr[ni], acc[mi][ni]);

        asm volatile("s_waitcnt lgkmcnt(0)" ::: "memory");
        __builtin_amdgcn_s_barrier();
    }

    const int mb = m0 + wr * 32, nb = n0 + wc * 64;
    if (is_out) {
        #pragma unroll
        for (int mi = 0; mi < 2; ++mi)
            #pragma unroll
            for (int ni = 0; ni < 4; ++ni) {
                const int n = nb + ni * 16 + lm;
                const int mr = mb + mi * 16 + l4 * 4;
                #pragma unroll
                for (int r = 0; r < 4; ++r)
                    Of[(size_t)(mr + r) * 1024 + n] = acc[mi][ni][r];
            }
    } else if (nb >= 2048) {            // V^T region
        #pragma unroll
        for (int mi = 0; mi < 2; ++mi)
            #pragma unroll
            for (int ni = 0; ni < 4; ++ni) {
                const int nv = nb - 2048 + ni * 16 + lm;
                const int m = mb + mi * 16 + l4 * 4;
                const int b = m >> 11, s = m & 2047, h = nv >> 6, d = nv & 63;
                ushort4 pk;
                pk.x = f2bf(acc[mi][ni][0]); pk.y = f2bf(acc[mi][ni][1]);
                pk.z = f2bf(acc[mi][ni][2]); pk.w = f2bf(acc[mi][ni][3]);
                *(ushort4*)(Ovt + (((size_t)(b * 16 + h) * 64 + d) * 2048 + s)) = pk;
            }
    } else {                            // Q (scaled) or K region
        ushort_t* O = (nb < 1024) ? Oq : Ok;
        const float qs = (nb < 1024) ? (float)QSCALE : 1.0f;
        const int nbase = nb & 1023;
        #pragma unroll
        for (int mi = 0; mi < 2; ++mi)
            #pragma unroll
            for (int ni = 0; ni < 4; ++ni) {
                const int n = nbase + ni * 16 + lm;
                const int h = n >> 6, d = n & 63;
                #pragma unroll
                for (int r = 0; r < 4; ++r) {
                    const int m = mb + mi * 16 + l4 * 4 + r;
                    const int b = m >> 11, s = m & 2047;
                    O[((size_t)(b * 16 + h) * 2048 + s) * 64 + d] =
                        f2bf(acc[mi][ni][r] * qs);
                }
            }
    }
}

// ---------------------------------------------------------------- attention
// (R18 structure, kept) Zero-shift softmax + 64KB LDS, 2 kv-groups x 4 q-waves.
__global__ __launch_bounds__(512) void attn_kernel(
    const ushort_t* __restrict__ Qg, const ushort_t* __restrict__ Kg,
    const ushort_t* __restrict__ Vtg, ushort_t* __restrict__ Og)
{
    __shared__ char smem[65536];
    // K: [g][buf] at g*16384 + buf*8192 ; V: 32768 + g*8192 ; P: 49152 + w*2048

    const int t = threadIdx.x, l = t & 63, w = t >> 6;
    const int l4 = l >> 4, lm = l & 15;
    const int kvg = w >> 2, qg = w & 3;        // 2 kv-groups x 4 q-waves
    const int bh = blockIdx.x;
    const int qt = 15 - (int)blockIdx.y;       // heavy q-tiles first
    const int q0w = qt * 128 + qg * 32;

    const ushort_t* Kbh = Kg + (size_t)bh * 2048 * 64;
    const ushort_t* Vbh = Vtg + (size_t)bh * 64 * 2048;

    bf16x8 qf[2][2];
    #pragma unroll
    for (int qi = 0; qi < 2; ++qi) {
        const ushort_t* qp = Qg + ((size_t)bh * 2048 + q0w + qi * 16 + lm) * 64 + l4 * 8;
        qf[qi][0] = *(const bf16x8*)qp;
        qf[qi][1] = *(const bf16x8*)(qp + 32);
    }
    bf16x8 ones;
    #pragma unroll
    for (int i = 0; i < 8; ++i) ones[i] = (short)0x3F80;

    f32x4 o[2][4] = {};
    f32x4 ol[2] = {};

    const int tg = t & 255;
    const int sr0 = tg >> 3, sc0 = tg & 7;
    const ushort_t* kp[2]; const ushort_t* vp[2];
    char* kd[2]; char* vd[2];
    #pragma unroll
    for (int i = 0; i < 2; ++i) {
        const int row = i * 32 + sr0;
        const int c = sc0 ^ (row & 7);
        kp[i] = Kbh + row * 64 + c * 8;
        vp[i] = Vbh + (size_t)row * 2048 + c * 8;
        kd[i] = smem + kvg * 16384 + i * 4096 + tg * 16;
        vd[i] = smem + 32768 + kvg * 8192 + i * 4096 + tg * 16;
    }
    const int pswz = (lm & 7) << 4;
    char* Pw = smem + 49152 + w * 2048;
    const ushort_t* Vgrp = (const ushort_t*)(smem + 32768 + kvg * 8192);

    const int nst = qt + 1;
    {   // prologue: stage K(0) -> buf 0
        const int kv0p = kvg * 64;
        #pragma unroll
        for (int i = 0; i < 2; ++i)
            async_copy16(kd[i], kp[i] + (size_t)kv0p * 64);
    }

    for (int s = 0; s < nst; ++s) {
        const int cur = s & 1;
        const int kv0 = (2 * s + kvg) * 64;
        #pragma unroll
        for (int i = 0; i < 2; ++i)
            async_copy16(vd[i], vp[i] + kv0);
        if (s + 1 < nst) {
            const int kv0n = (2 * (s + 1) + kvg) * 64;
            #pragma unroll
            for (int i = 0; i < 2; ++i)
                async_copy16(kd[i] + (cur ^ 1) * 8192, kp[i] + (size_t)kv0n * 64);
            asm volatile("s_waitcnt vmcnt(4)" ::: "memory");
        } else {
            asm volatile("s_waitcnt vmcnt(2)" ::: "memory");
        }
        __builtin_amdgcn_s_barrier();          // B1: K(t) visible

        const bool active = (s + 1 < nst) || (q0w + 31 >= kv0);
        const bool last = (s + 1 == nst);
        const ushort_t* Kgrp = (const ushort_t*)(smem + kvg * 16384 + cur * 8192);

        f32x4 sf[2][4];
        if (active) {
            #pragma unroll
            for (int qi = 0; qi < 2; ++qi)
                #pragma unroll
                for (int cf = 0; cf < 4; ++cf) sf[qi][cf] = (f32x4){0,0,0,0};
            #pragma unroll
            for (int ks = 0; ks < 2; ++ks)
                #pragma unroll
                for (int cf = 0; cf < 4; ++cf) {
                    const int rowK = cf * 16 + lm;
                    const int ch = l4 + 4 * ks;
                    bf16x8 kf = *(const bf16x8*)(Kgrp + rowK * 64 + ((ch ^ (rowK & 7)) << 3));
                    sf[0][cf] = MFMA16(kf, qf[0][ks], sf[0][cf]);
                    sf[1][cf] = MFMA16(kf, qf[1][ks], sf[1][cf]);
                }
            {
                const int qrow = q0w + 0 * 16 + lm;
                #pragma unroll
                for (int cf = 0; cf < 4; ++cf) {
                    f32x4 sv = sf[0][cf];
                    if (last) {
                        #pragma unroll
                        for (int r = 0; r < 4; ++r)
                            if (kv0 + cf * 16 + l4 * 4 + r > qrow) sv[r] = -30000.f;
                    }
                    float p0 = __builtin_amdgcn_exp2f(sv[0]);
                    float p1 = __builtin_amdgcn_exp2f(sv[1]);
                    float p2 = __builtin_amdgcn_exp2f(sv[2]);
                    float p3 = __builtin_amdgcn_exp2f(sv[3]);
                    __hip_bfloat162 b01 = __float22bfloat162_rn(make_float2(p0, p1));
                    __hip_bfloat162 b23 = __float22bfloat162_rn(make_float2(p2, p3));
                    uint2 pkv;
                    __builtin_memcpy(&pkv.x, &b01, 4);
                    __builtin_memcpy(&pkv.y, &b23, 4);
                    *(uint2*)(Pw + ((lm * 128 + cf * 32 + l4 * 8) ^ pswz)) = pkv;
                }
            }
        }
        asm volatile("s_waitcnt vmcnt(2)" ::: "memory");
        if (last) asm volatile("s_waitcnt vmcnt(0)" ::: "memory");
        __builtin_amdgcn_s_barrier();          // B2: V(t) visible

        if (active) {
            #pragma unroll
            for (int ks = 0; ks < 2; ++ks) {
                bf16x8 pf = *(const bf16x8*)(Pw + ((lm * 128 + ks * 64 + l4 * 16) ^ pswz));
                #pragma unroll
                for (int df = 0; df < 4; ++df) {
                    const int rowV = df * 16 + lm;
                    const int ch = l4 + 4 * ks;
                    bf16x8 vf = *(const bf16x8*)(Vgrp + rowV * 64 + ((ch ^ (rowV & 7)) << 3));
                    o[0][df] = MFMA16(vf, pf, o[0][df]);
                }
                ol[0] = MFMA16(ones, pf, ol[0]);
            }
            {
                const int qrow = q0w + 1 * 16 + lm;
                #pragma unroll
                for (int cf = 0; cf < 4; ++cf) {
                    f32x4 sv = sf[1][cf];
                    if (last) {
                        #pragma unroll
                        for (int r = 0; r < 4; ++r)
                            if (kv0 + cf * 16 + l4 * 4 + r > qrow) sv[r] = -30000.f;
                    }
                    float p0 = __builtin_amdgcn_exp2f(sv[0]);
                    float p1 = __builtin_amdgcn_exp2f(sv[1]);
                    float p2 = __builtin_amdgcn_exp2f(sv[2]);
                    float p3 = __builtin_amdgcn_exp2f(sv[3]);
                    __hip_bfloat162 b01 = __float22bfloat162_rn(make_float2(p0, p1));
                    __hip_bfloat162 b23 = __float22bfloat162_rn(make_float2(p2, p3));
                    uint2 pkv;
                    __builtin_memcpy(&pkv.x, &b01, 4);
                    __builtin_memcpy(&pkv.y, &b23, 4);
                    *(uint2*)(Pw + ((lm * 128 + cf * 32 + l4 * 8) ^ pswz)) = pkv;
                }
            }
            #pragma unroll
            for (int ks = 0; ks < 2; ++ks) {
                bf16x8 pf = *(const bf16x8*)(Pw + ((lm * 128 + ks * 64 + l4 * 16) ^ pswz));
                #pragma unroll
                for (int df = 0; df < 4; ++df) {
                    const int rowV = df * 16 + lm;
                    const int ch = l4 + 4 * ks;
                    bf16x8 vf = *(const bf16x8*)(Vgrp + rowV * 64 + ((ch ^ (rowV & 7)) << 3));
                    o[1][df] = MFMA16(vf, pf, o[1][df]);
                }
                ol[1] = MFMA16(ones, pf, ol[1]);
            }
        }
        asm volatile("s_waitcnt lgkmcnt(0)" ::: "memory");
        __builtin_amdgcn_s_barrier();          // B3: WAR fence
    }

    // ---- merge: plain sum (both groups share the zero shift) ----
    float* sc = (float*)smem;
    const int mb_ = (qg * 64 + l) * 35;
    if (kvg == 1) {
        #pragma unroll
        for (int qi = 0; qi < 2; ++qi) {
            #pragma unroll
            for (int df = 0; df < 4; ++df)
                #pragma unroll
                for (int r = 0; r < 4; ++r)
                    sc[mb_ + qi * 17 + df * 4 + r] = o[qi][df][r];
            sc[mb_ + qi * 17 + 16] = ol[qi][0];
        }
    }
    __syncthreads();
    if (kvg == 0) {
        const int b = bh >> 4, h = bh & 15;
        #pragma unroll
        for (int qi = 0; qi < 2; ++qi) {
            const float lB = sc[mb_ + qi * 17 + 16];
            const float inv = 1.f / (ol[qi][0] + lB);
            const int srow_o = q0w + qi * 16 + lm;
            #pragma unroll
            for (int df = 0; df < 4; ++df) {
                ushort4 pk4;
                float v0 = (o[qi][df][0] + sc[mb_ + qi * 17 + df * 4 + 0]) * inv;
                float v1 = (o[qi][df][1] + sc[mb_ + qi * 17 + df * 4 + 1]) * inv;
                float v2 = (o[qi][df][2] + sc[mb_ + qi * 17 + df * 4 + 2]) * inv;
                float v3 = (o[qi][df][3] + sc[mb_ + qi * 17 + df * 4 + 3]) * inv;
                pk4.x = f2bf(v0); pk4.y = f2bf(v1); pk4.z = f2bf(v2); pk4.w = f2bf(v3);
                *(ushort4*)&Og[((size_t)(b * 2048 + srow_o)) * 1024 + h * 64 + df * 16 + l4 * 4] = pk4;
            }
        }
    }
}

// ---------------------------------------------------------------- launch
extern "C" void kernel_launch(void* const* d_in, const int* in_sizes, int n_in,
                              void* d_out, int out_size, void* d_ws, size_t ws_size,
                              hipStream_t stream)
{
    const float* x  = (const float*)d_in[0];
    const float* Wq = (const float*)d_in[1];
    const float* Wk = (const float*)d_in[2];
    const float* Wv = (const float*)d_in[3];
    const float* Wo = (const float*)d_in[4];

    ushort_t* ws  = (ushort_t*)d_ws;
    ushort_t* xb  = ws;
    ushort_t* wqb = ws + 4194304;          // Wq|Wk|Wv contiguous = [3072][1024]
    ushort_t* wob = ws + 7340032;
    ushort_t* Qw  = ws + 8388608;          // [bh][s][64] (pre-scaled)
    ushort_t* Kw  = ws + 12582912;         // [bh][s][64]
    ushort_t* Vtw = ws + 16777216;         // [bh][d][s]
    ushort_t* Aow = ws + 20971520;         // [b][s][1024]

    cvt_kernel<<<4096, 256, 0, stream>>>(x, Wq, Wk, Wv, Wo, ws);
    gemm_bt<<<dim3(24, 32), 512, 0, stream>>>(xb, wqb, Qw, Kw, Vtw, nullptr, 0);
    attn_kernel<<<dim3(32, 16), 512, 0, stream>>>(Qw, Kw, Vtw, Aow);
    gemm_bt<<<dim3(8, 32), 512, 0, stream>>>(Aow, wob, nullptr, nullptr, nullptr,
                                             (float*)d_out, 1);
}